// Round 9
// baseline (1251.275 us; speedup 1.0000x reference)
//
#include <hip/hip_runtime.h>
#include <hip/hip_bf16.h>
#include <stdint.h>

#define N_NODES 20000
#define N_EDGES 320000
#define DIM 300
#define ADIM 320              // padded activation stride (cols 300..319 = 0)
#define ROWS_PAD 20096        // 157 * 128
#define N_LAYERS 5
#define EDIM 7
#define NGRAPH 128
#define NCLS 6
#define DHALF 150
#define BN_EPS 1e-5f

#define CDIV(a, b) (((a) + (b) - 1) / (b))

typedef short bf16x8 __attribute__((ext_vector_type(8)));
typedef float f32x4 __attribute__((ext_vector_type(4)));
typedef unsigned short ushort_t;

__device__ __forceinline__ float bf2f(ushort_t u) {
    union { float f; uint32_t i; } v; v.i = ((uint32_t)u) << 16; return v.f;
}
__device__ __forceinline__ ushort_t f2bf(float f) {
    union { float f; uint32_t i; } v; v.f = f;
    uint32_t x = v.i;
    x += 0x7FFFu + ((x >> 16) & 1u);   // RTN-even (no inf/nan expected)
    return (ushort_t)(x >> 16);
}

// ---------------- node encoder: h_bf[n][d] = bf16(node_emb[x[n]][d]) --------
__global__ void node_enc_kernel(const int* __restrict__ x,
                                const float* __restrict__ node_emb,
                                ushort_t* __restrict__ h_bf) {
    int idx = blockIdx.x * blockDim.x + threadIdx.x;  // 20000*40
    if (idx >= N_NODES * 40) return;
    int n = idx / 40;
    int d0 = (idx - n * 40) * 8;
    const float* src = node_emb + (size_t)x[n] * DIM;
    union { ushort_t u[8]; uint4 v; } o;
#pragma unroll
    for (int j = 0; j < 8; ++j) {
        int d = d0 + j;
        o.u[j] = (d < DIM) ? f2bf(src[d]) : (ushort_t)0;
    }
    *(uint4*)(h_bf + (size_t)n * ADIM + d0) = o.v;
}

// -------- W transpose+convert: Wt[mat][n][k] = bf16(W[k][n]), k fastest -----
__global__ void wt_prep_kernel(const float* __restrict__ W1,
                               const float* __restrict__ W2,
                               ushort_t* __restrict__ Wt) {
    int idx = blockIdx.x * blockDim.x + threadIdx.x;  // 10*320*320
    if (idx >= 10 * ADIM * ADIM) return;
    int mat = idx / (ADIM * ADIM);
    int rem = idx - mat * ADIM * ADIM;
    int n = rem / ADIM;          // output col (row of Wt)
    int k = rem - n * ADIM;      // k fastest -> coalesced writes
    const float* src = (mat < 5) ? (W1 + (size_t)mat * DIM * DIM)
                                 : (W2 + (size_t)(mat - 5) * DIM * DIM);
    float v = (k < DIM && n < DIM) ? src[(size_t)k * DIM + n] : 0.0f;
    Wt[(size_t)mat * ADIM * ADIM + (size_t)n * ADIM + k] = f2bf(v);
}

// ---------------- CSR build ----------------
__global__ void deg_kernel(const int* __restrict__ dst, int* __restrict__ deg) {
    int e = blockIdx.x * blockDim.x + threadIdx.x;
    if (e < N_EDGES) atomicAdd(&deg[dst[e]], 1);
}

__global__ void scan_kernel(const int* __restrict__ deg, int* __restrict__ off,
                            int* __restrict__ cur) {
    __shared__ int sh[1024];
    int t = threadIdx.x;
    int base = t * 20;
    int local[20];
    int s = 0;
#pragma unroll
    for (int j = 0; j < 20; ++j) {
        int i = base + j;
        int v = (i < N_NODES) ? deg[i] : 0;
        local[j] = v;
        s += v;
    }
    sh[t] = s;
    __syncthreads();
    for (int o = 1; o < 1024; o <<= 1) {
        int v = sh[t];
        int add = (t >= o) ? sh[t - o] : 0;
        __syncthreads();
        sh[t] = v + add;
        __syncthreads();
    }
    int run = (t > 0) ? sh[t - 1] : 0;
#pragma unroll
    for (int j = 0; j < 20; ++j) {
        int i = base + j;
        if (i < N_NODES) {
            off[i] = run;
            cur[i] = run;
            run += local[j];
        }
    }
    if (t == 1023) off[N_NODES] = sh[1023];
}

__global__ void scatter_kernel(const int* __restrict__ src,
                               const int* __restrict__ dst,
                               const float* __restrict__ edge_attr,
                               int* __restrict__ cur,
                               int* __restrict__ perm_src,
                               float* __restrict__ pea) {
    int e = blockIdx.x * blockDim.x + threadIdx.x;
    if (e >= N_EDGES) return;
    int d = dst[e];
    int p = atomicAdd(&cur[d], 1);
    perm_src[p] = src[e];
    const float* ar = edge_attr + (size_t)e * EDIM;
    float* pr = pea + (size_t)p * 8;
#pragma unroll
    for (int j = 0; j < EDIM; ++j) pr[j] = ar[j];
    pr[7] = 0.0f;
}

// ------- TWO nodes per wave (2 independent gather chains for 2x MLP) --------
// z = (1+eps)*h + sum relu(h[src]+ea); block 0 zeroes the BN stat buffers.
#define MSG_BLOCKS 2500
__global__ __launch_bounds__(256) void msg_kernel(
    const ushort_t* __restrict__ h_bf, ushort_t* __restrict__ z_bf,
    const int* __restrict__ off, const int* __restrict__ perm_src,
    const float* __restrict__ pea,
    const float* __restrict__ edge_W, const float* __restrict__ edge_b,
    const float* __restrict__ eps, int layer,
    float* __restrict__ s1a, float* __restrict__ s2a,
    float* __restrict__ s1b, float* __restrict__ s2b) {
    if (blockIdx.x == 0) {
        for (int d = threadIdx.x; d < ADIM; d += 256) {
            s1a[d] = 0.f; s2a[d] = 0.f; s1b[d] = 0.f; s2b[d] = 0.f;
        }
    }
    int w = (blockIdx.x * 256 + threadIdx.x) >> 6;
    if (w >= N_NODES / 2) return;
    int lane = threadIdx.x & 63;
    int nA = 2 * w, nB = 2 * w + 1;

    float ew[5][7], eb[5];
#pragma unroll
    for (int c = 0; c < 5; ++c) {
        int d = c * 64 + lane;
        bool ok = (d < DIM);
        eb[c] = ok ? edge_b[d] : 0.0f;
#pragma unroll
        for (int j = 0; j < EDIM; ++j)
            ew[c][j] = ok ? edge_W[j * DIM + d] : 0.0f;
    }
    float epsv = 1.0f + eps[layer];

    int a0 = off[nA];
    int b0 = off[nB];          // == end of A's range
    int b1 = off[nB + 1];
    int lenA = b0 - a0, lenB = b1 - b0;
    int kmax = lenA > lenB ? lenA : lenB;

    float accA[5] = {0.f, 0.f, 0.f, 0.f, 0.f};
    float accB[5] = {0.f, 0.f, 0.f, 0.f, 0.f};

    for (int k = 0; k < kmax; ++k) {
        bool doA = (k < lenA), doB = (k < lenB);
        int sA = 0, sB = 0;
        if (doA) sA = perm_src[a0 + k];
        if (doB) sB = perm_src[b0 + k];
        float4 aA03, aA47, aB03, aB47;
        if (doA) {
            const float* ap = pea + (size_t)(a0 + k) * 8;
            aA03 = *(const float4*)ap;
            aA47 = *(const float4*)(ap + 4);
        }
        if (doB) {
            const float* ap = pea + (size_t)(b0 + k) * 8;
            aB03 = *(const float4*)ap;
            aB47 = *(const float4*)(ap + 4);
        }
        float hA[5], hB[5];
        if (doA) {
            const ushort_t* hr = h_bf + (size_t)sA * ADIM;
#pragma unroll
            for (int c = 0; c < 5; ++c) hA[c] = bf2f(hr[c * 64 + lane]);
        }
        if (doB) {
            const ushort_t* hr = h_bf + (size_t)sB * ADIM;
#pragma unroll
            for (int c = 0; c < 5; ++c) hB[c] = bf2f(hr[c * 64 + lane]);
        }
        if (doA) {
#pragma unroll
            for (int c = 0; c < 5; ++c) {
                float ea = eb[c];
                ea += aA03.x * ew[c][0];
                ea += aA03.y * ew[c][1];
                ea += aA03.z * ew[c][2];
                ea += aA03.w * ew[c][3];
                ea += aA47.x * ew[c][4];
                ea += aA47.y * ew[c][5];
                ea += aA47.z * ew[c][6];
                accA[c] += fmaxf(hA[c] + ea, 0.0f);
            }
        }
        if (doB) {
#pragma unroll
            for (int c = 0; c < 5; ++c) {
                float ea = eb[c];
                ea += aB03.x * ew[c][0];
                ea += aB03.y * ew[c][1];
                ea += aB03.z * ew[c][2];
                ea += aB03.w * ew[c][3];
                ea += aB47.x * ew[c][4];
                ea += aB47.y * ew[c][5];
                ea += aB47.z * ew[c][6];
                accB[c] += fmaxf(hB[c] + ea, 0.0f);
            }
        }
    }

    {
        const ushort_t* hn = h_bf + (size_t)nA * ADIM;
        ushort_t* zr = z_bf + (size_t)nA * ADIM;
#pragma unroll
        for (int c = 0; c < 5; ++c) {
            int d = c * 64 + lane;
            zr[d] = f2bf(epsv * bf2f(hn[d]) + accA[c]);
        }
    }
    {
        const ushort_t* hn = h_bf + (size_t)nB * ADIM;
        ushort_t* zr = z_bf + (size_t)nB * ADIM;
#pragma unroll
        for (int c = 0; c < 5; ++c) {
            int d = c * 64 + lane;
            zr[d] = f2bf(epsv * bf2f(hn[d]) + accB[c]);
        }
    }
}

// ---------------- bf16 MFMA GEMM + fused BN stats (+optional fused BN on A) --
// Block 128x80, 4 waves (wave tile 32x80), K-step 64, grid 157x4 = 628 blocks.
// BNA=false: A = Abf (bf16 [ROWS_PAD][ADIM]).
// BNA=true:  A = relu(BN(Af32)) via raw sums in_s1/in_s2 + gamma/beta, staged
//            on the fly (NaN/poison in pad rows is squashed by fmaxf).
// Epilogue: Y f32 (rows<20000, cols<300) + per-column sum/sumsq -> gs1/gs2.
__device__ __forceinline__ int swz(int row, int k8) {
    return ((row << 7) + (k8 << 4)) ^ ((row & 7) << 4);
}

template <bool BNA>
__global__ __launch_bounds__(256) void gemm_kernel(
    const ushort_t* __restrict__ Abf, const float* __restrict__ Af32,
    const ushort_t* __restrict__ Wt, float* __restrict__ Y,
    const float* __restrict__ in_s1, const float* __restrict__ in_s2,
    const float* __restrict__ bn_g, const float* __restrict__ bn_be,
    float* __restrict__ gs1, float* __restrict__ gs2) {
    __shared__ ushort_t sA[128 * 64];   // 16 KB, swizzled
    __shared__ ushort_t sB[80 * 64];    // 10 KB, swizzled
    __shared__ float sRed[4 * 160];     // stats cross-wave reduce
    __shared__ float s_scale[ADIM], s_shift[ADIM];
    char* sAc = (char*)sA;
    char* sBc = (char*)sB;

    int tid = threadIdx.x;
    int lane = tid & 63;
    int wv = tid >> 6;                  // wave -> 32-row strip
    int row0 = blockIdx.x * 128;
    int col0 = blockIdx.y * 80;
    int l15 = lane & 15, l4 = lane >> 4;

    if (BNA) {
        for (int d = tid; d < ADIM; d += 256) {
            float sc = 0.f, sh = 0.f;
            if (d < DIM) {
                const float invn = 1.0f / (float)N_NODES;
                float mean = in_s1[d] * invn;
                float var = in_s2[d] * invn - mean * mean;
                sc = bn_g[d] * rsqrtf(var + BN_EPS);
                sh = bn_be[d] - mean * sc;
            }
            s_scale[d] = sc;
            s_shift[d] = sh;
        }
        __syncthreads();
    }

    f32x4 acc[2][5];
#pragma unroll
    for (int m = 0; m < 2; ++m)
#pragma unroll
        for (int n = 0; n < 5; ++n) acc[m][n] = (f32x4){0.f, 0.f, 0.f, 0.f};

    for (int kt = 0; kt < 5; ++kt) {
        int k0 = kt * 64;
        // stage A: 128x64 -> 1024 16B chunks, 4/thread
#pragma unroll
        for (int it = 0; it < 4; ++it) {
            int idx = tid + it * 256;
            int row = idx >> 3, k8 = idx & 7;
            if (!BNA) {
                const ushort_t* g = Abf + (size_t)(row0 + row) * ADIM + k0 + k8 * 8;
                *(uint4*)(sAc + swz(row, k8)) = *(const uint4*)g;
            } else {
                const float* g = Af32 + (size_t)(row0 + row) * ADIM + k0 + k8 * 8;
                float4 y0 = *(const float4*)g;
                float4 y1 = *(const float4*)(g + 4);
                float yv[8] = {y0.x, y0.y, y0.z, y0.w, y1.x, y1.y, y1.z, y1.w};
                int kb = k0 + k8 * 8;
                union { ushort_t u[8]; uint4 v; } o;
#pragma unroll
                for (int j = 0; j < 8; ++j)
                    o.u[j] = f2bf(fmaxf(yv[j] * s_scale[kb + j] + s_shift[kb + j], 0.0f));
                *(uint4*)(sAc + swz(row, k8)) = o.v;
            }
        }
        // stage B: 80x64 -> 640 chunks
#pragma unroll
        for (int it = 0; it < 3; ++it) {
            int idx = tid + it * 256;
            if (idx < 640) {
                int row = idx >> 3, k8 = idx & 7;
                const ushort_t* g = Wt + (size_t)(col0 + row) * ADIM + k0 + k8 * 8;
                *(uint4*)(sBc + swz(row, k8)) = *(const uint4*)g;
            }
        }
        __syncthreads();

#pragma unroll
        for (int kk = 0; kk < 2; ++kk) {
            bf16x8 a[2], b[5];
#pragma unroll
            for (int m = 0; m < 2; ++m)
                a[m] = *(const bf16x8*)(sAc + swz(wv * 32 + m * 16 + l15, kk * 4 + l4));
#pragma unroll
            for (int n = 0; n < 5; ++n)
                b[n] = *(const bf16x8*)(sBc + swz(n * 16 + l15, kk * 4 + l4));
#pragma unroll
            for (int m = 0; m < 2; ++m)
#pragma unroll
                for (int n = 0; n < 5; ++n)
                    acc[m][n] = __builtin_amdgcn_mfma_f32_16x16x32_bf16(
                        a[m], b[n], acc[m][n], 0, 0, 0);
        }
        __syncthreads();
    }

    // ---- write Y + per-wave column stats ----
#pragma unroll
    for (int n = 0; n < 5; ++n) {
        int col = col0 + n * 16 + l15;
        float s1 = 0.f, s2 = 0.f;
#pragma unroll
        for (int m = 0; m < 2; ++m) {
#pragma unroll
            for (int r = 0; r < 4; ++r) {
                int row = row0 + wv * 32 + m * 16 + l4 * 4 + r;
                float v = acc[m][n][r];
                if (row < N_NODES && col < DIM) {
                    Y[(size_t)row * ADIM + col] = v;
                    s1 += v;
                    s2 += v * v;
                }
            }
        }
        s1 += __shfl_xor(s1, 16, 64);
        s1 += __shfl_xor(s1, 32, 64);
        s2 += __shfl_xor(s2, 16, 64);
        s2 += __shfl_xor(s2, 32, 64);
        if (l4 == 0) {
            sRed[wv * 160 + n * 16 + l15] = s1;
            sRed[wv * 160 + 80 + n * 16 + l15] = s2;
        }
    }
    __syncthreads();
    if (tid < 160) {
        float v = sRed[tid] + sRed[160 + tid] + sRed[320 + tid] + sRed[480 + tid];
        int cc = (tid < 80) ? tid : tid - 80;
        int col = col0 + cc;
        if (col < DIM) atomicAdd(((tid < 80) ? gs1 : gs2) + col, v);
    }
}

// ------- h_bf = bf16(relu(BN(y))) with scale/shift computed inline ----------
__global__ void apply_bn_kernel(const float* __restrict__ y,
                                const float* __restrict__ s1,
                                const float* __restrict__ s2,
                                const float* __restrict__ g,
                                const float* __restrict__ be,
                                ushort_t* __restrict__ out_bf) {
    int idx = blockIdx.x * blockDim.x + threadIdx.x;  // 20000*40
    if (idx >= N_NODES * 40) return;
    int n = idx / 40;
    int d0 = (idx - n * 40) * 8;
    const float* yr = y + (size_t)n * ADIM + d0;
    const float invn = 1.0f / (float)N_NODES;
    union { ushort_t u[8]; uint4 v; } o;
#pragma unroll
    for (int j = 0; j < 8; ++j) {
        int d = d0 + j;
        float r = 0.0f;
        if (d < DIM) {
            float mean = s1[d] * invn;
            float var = s2[d] * invn - mean * mean;
            float sc = g[d] * rsqrtf(var + BN_EPS);
            float sh = be[d] - mean * sc;
            r = fmaxf(yr[j] * sc + sh, 0.0f);
        }
        o.u[j] = f2bf(r);
    }
    *(uint4*)(out_bf + (size_t)n * ADIM + d0) = o.v;
}

// ---------------- pooling: sorted batch -> segmented reduction --------------
__device__ __forceinline__ int lbound(const int* __restrict__ batch, int g) {
    int lo = 0, hi = N_NODES;
    while (lo < hi) {
        int mid = (lo + hi) >> 1;
        if (batch[mid] < g) lo = mid + 1; else hi = mid;
    }
    return lo;
}

__global__ void pool_kernel(const ushort_t* __restrict__ h_bf,
                            const int* __restrict__ batch,
                            float* __restrict__ pooled,
                            float* __restrict__ counts) {
    int g = blockIdx.x;
    int chunk = blockIdx.y;   // 0..3
    int d = threadIdx.x;      // 320
    int s = lbound(batch, g);
    int e = lbound(batch, g + 1);
    if (chunk == 0 && d == 0) counts[g] = (float)(e - s);
    if (d >= DIM) return;
    int len = e - s;
    int per = (len + 3) >> 2;
    int r0 = s + chunk * per;
    int r1 = min(r0 + per, e);
    float a = 0.f;
    for (int r = r0; r < r1; ++r) a += bf2f(h_bf[(size_t)r * ADIM + d]);
    if (r1 > r0) atomicAdd(&pooled[(size_t)g * DIM + d], a);
}

// ---------------- MLP head ----------------
__global__ void mlp1_kernel(const float* __restrict__ pooled,
                            const float* __restrict__ counts,
                            const float* __restrict__ Wc1,
                            const float* __restrict__ bc1,
                            float* __restrict__ hidden) {
    int g = blockIdx.x;
    int j = threadIdx.x;  // 192
    if (j >= DHALF) return;
    float inv = 1.0f / fmaxf(counts[g], 1.0f);
    const float* prow = pooled + (size_t)g * DIM;
    float acc = 0.0f;
    for (int k = 0; k < DIM; ++k) acc += prow[k] * Wc1[k * DHALF + j];
    hidden[g * DHALF + j] = fmaxf(acc * inv + bc1[j], 0.0f);
}

__global__ void mlp2_kernel(const float* __restrict__ hidden,
                            const float* __restrict__ Wc2,
                            const float* __restrict__ bc2,
                            float* __restrict__ out) {
    int idx = blockIdx.x * blockDim.x + threadIdx.x;
    if (idx >= NGRAPH * NCLS) return;
    int g = idx / NCLS;
    int c = idx - g * NCLS;
    const float* hrow = hidden + g * DHALF;
    float acc = bc2[c];
    for (int j = 0; j < DHALF; ++j) acc += hrow[j] * Wc2[j * NCLS + c];
    out[idx] = acc;
}

extern "C" void kernel_launch(void* const* d_in, const int* in_sizes, int n_in,
                              void* d_out, int out_size, void* d_ws, size_t ws_size,
                              hipStream_t stream) {
    const int*   x         = (const int*)d_in[0];
    const int*   edge_index= (const int*)d_in[1];
    const float* edge_attr = (const float*)d_in[2];
    const int*   batch     = (const int*)d_in[3];
    const float* node_emb  = (const float*)d_in[4];
    const float* edge_W    = (const float*)d_in[5];
    const float* edge_b    = (const float*)d_in[6];
    const float* eps       = (const float*)d_in[7];
    const float* W1        = (const float*)d_in[8];
    const float* g1        = (const float*)d_in[10];
    const float* be1       = (const float*)d_in[11];
    const float* W2        = (const float*)d_in[12];
    const float* g2        = (const float*)d_in[14];
    const float* be2       = (const float*)d_in[15];
    const float* Wc1       = (const float*)d_in[16];
    const float* bc1       = (const float*)d_in[17];
    const float* Wc2       = (const float*)d_in[18];
    const float* bc2       = (const float*)d_in[19];
    float* out = (float*)d_out;

    const int* src = edge_index;
    const int* dst = edge_index + N_EDGES;

    char* w = (char*)d_ws;
    size_t cur_off = 0;
    auto alloc = [&](size_t bytes) {
        char* p = w + cur_off;
        cur_off += (bytes + 63) & ~(size_t)63;
        return p;
    };
    const size_t AROW = (size_t)ROWS_PAD * ADIM;
    ushort_t* h_bf  = (ushort_t*)alloc(AROW * 2);
    ushort_t* zab   = (ushort_t*)alloc(AROW * 2);
    float*    Ybuf  = (float*)alloc(AROW * 4);
    float*    Y2buf = (float*)alloc(AROW * 4);
    ushort_t* Wt    = (ushort_t*)alloc((size_t)10 * ADIM * ADIM * 2);
    int*      deg   = (int*)alloc(N_NODES * 4);
    int*      off   = (int*)alloc((N_NODES + 1) * 4);
    int*      curp  = (int*)alloc(N_NODES * 4);
    int*      psrc  = (int*)alloc((size_t)N_EDGES * 4);
    float*    pea   = (float*)alloc((size_t)N_EDGES * 8 * 4);
    float*    s1a   = (float*)alloc(ADIM * 4);
    float*    s2a   = (float*)alloc(ADIM * 4);
    float*    s1b   = (float*)alloc(ADIM * 4);
    float*    s2b   = (float*)alloc(ADIM * 4);
    float*    pooled= (float*)alloc((size_t)NGRAPH * DIM * 4);
    float*    counts= (float*)alloc(NGRAPH * 4);
    float*    hidden= (float*)alloc((size_t)NGRAPH * DHALF * 4);

    // ---- prep ----
    hipMemsetAsync(deg, 0, N_NODES * 4, stream);
    hipMemsetAsync(zab + (size_t)N_NODES * ADIM, 0,
                   (size_t)(ROWS_PAD - N_NODES) * ADIM * 2, stream);

    node_enc_kernel<<<CDIV(N_NODES * 40, 256), 256, 0, stream>>>(x, node_emb, h_bf);
    wt_prep_kernel<<<CDIV(10 * ADIM * ADIM, 256), 256, 0, stream>>>(W1, W2, Wt);
    deg_kernel<<<CDIV(N_EDGES, 256), 256, 0, stream>>>(dst, deg);
    scan_kernel<<<1, 1024, 0, stream>>>(deg, off, curp);
    scatter_kernel<<<CDIV(N_EDGES, 256), 256, 0, stream>>>(src, dst, edge_attr,
                                                           curp, psrc, pea);

    dim3 ggrid(ROWS_PAD / 128, 4);  // 157 x 4

    for (int i = 0; i < N_LAYERS; ++i) {
        // z = (1+eps)*h + agg; block 0 zeroes stat buffers
        msg_kernel<<<MSG_BLOCKS, 256, 0, stream>>>(h_bf, zab, off, psrc, pea,
                                                   edge_W, edge_b, eps, i,
                                                   s1a, s2a, s1b, s2b);
        // Y = z @ W1, stats -> s1a/s2a
        gemm_kernel<false><<<ggrid, 256, 0, stream>>>(
            zab, nullptr, Wt + (size_t)i * ADIM * ADIM, Ybuf,
            nullptr, nullptr, nullptr, nullptr, s1a, s2a);
        // Y2 = relu(BN1(Y)) @ W2 (BN fused into A staging), stats -> s1b/s2b
        gemm_kernel<true><<<ggrid, 256, 0, stream>>>(
            nullptr, Ybuf, Wt + (size_t)(5 + i) * ADIM * ADIM, Y2buf,
            s1a, s2a, g1 + i * DIM, be1 + i * DIM, s1b, s2b);
        // h = relu(BN2(Y2))
        apply_bn_kernel<<<CDIV(N_NODES * 40, 256), 256, 0, stream>>>(
            Y2buf, s1b, s2b, g2 + i * DIM, be2 + i * DIM, h_bf);
    }

    hipMemsetAsync(pooled, 0, (size_t)NGRAPH * DIM * 4, stream);
    dim3 pgrid(NGRAPH, 4);
    pool_kernel<<<pgrid, ADIM, 0, stream>>>(h_bf, batch, pooled, counts);
    mlp1_kernel<<<NGRAPH, 192, 0, stream>>>(pooled, counts, Wc1, bc1, hidden);
    mlp2_kernel<<<CDIV(NGRAPH * NCLS, 256), 256, 0, stream>>>(hidden, Wc2, bc2, out);
}

// Round 10
// 960.659 us; speedup vs baseline: 1.3025x; 1.3025x over previous
//
#include <hip/hip_runtime.h>
#include <hip/hip_bf16.h>
#include <stdint.h>

#define N_NODES 20000
#define N_EDGES 320000
#define DIM 300
#define ADIM 320              // padded activation stride (cols 300..319 = 0)
#define ROWS_PAD 20096        // 157 * 128
#define N_LAYERS 5
#define EDIM 7
#define NGRAPH 128
#define NCLS 6
#define DHALF 150
#define BN_EPS 1e-5f

#define CDIV(a, b) (((a) + (b) - 1) / (b))

typedef short bf16x8 __attribute__((ext_vector_type(8)));
typedef float f32x4 __attribute__((ext_vector_type(4)));
typedef unsigned short ushort_t;

__device__ __forceinline__ float bf2f(ushort_t u) {
    union { float f; uint32_t i; } v; v.i = ((uint32_t)u) << 16; return v.f;
}
__device__ __forceinline__ ushort_t f2bf(float f) {
    union { float f; uint32_t i; } v; v.f = f;
    uint32_t x = v.i;
    x += 0x7FFFu + ((x >> 16) & 1u);   // RTN-even (no inf/nan expected)
    return (ushort_t)(x >> 16);
}

// ---------------- node encoder: h_bf[n][d] = bf16(node_emb[x[n]][d]) --------
__global__ void node_enc_kernel(const int* __restrict__ x,
                                const float* __restrict__ node_emb,
                                ushort_t* __restrict__ h_bf) {
    int idx = blockIdx.x * blockDim.x + threadIdx.x;  // 20000*40
    if (idx >= N_NODES * 40) return;
    int n = idx / 40;
    int d0 = (idx - n * 40) * 8;
    const float* src = node_emb + (size_t)x[n] * DIM;
    union { ushort_t u[8]; uint4 v; } o;
#pragma unroll
    for (int j = 0; j < 8; ++j) {
        int d = d0 + j;
        o.u[j] = (d < DIM) ? f2bf(src[d]) : (ushort_t)0;
    }
    *(uint4*)(h_bf + (size_t)n * ADIM + d0) = o.v;
}

// -------- W transpose+convert: Wt[mat][n][k] = bf16(W[k][n]), k fastest -----
__global__ void wt_prep_kernel(const float* __restrict__ W1,
                               const float* __restrict__ W2,
                               ushort_t* __restrict__ Wt) {
    int idx = blockIdx.x * blockDim.x + threadIdx.x;  // 10*320*320
    if (idx >= 10 * ADIM * ADIM) return;
    int mat = idx / (ADIM * ADIM);
    int rem = idx - mat * ADIM * ADIM;
    int n = rem / ADIM;          // output col (row of Wt)
    int k = rem - n * ADIM;      // k fastest -> coalesced writes
    const float* src = (mat < 5) ? (W1 + (size_t)mat * DIM * DIM)
                                 : (W2 + (size_t)(mat - 5) * DIM * DIM);
    float v = (k < DIM && n < DIM) ? src[(size_t)k * DIM + n] : 0.0f;
    Wt[(size_t)mat * ADIM * ADIM + (size_t)n * ADIM + k] = f2bf(v);
}

// ---------------- CSR build ----------------
__global__ void deg_kernel(const int* __restrict__ dst, int* __restrict__ deg) {
    int e = blockIdx.x * blockDim.x + threadIdx.x;
    if (e < N_EDGES) atomicAdd(&deg[dst[e]], 1);
}

__global__ void scan_kernel(const int* __restrict__ deg, int* __restrict__ off,
                            int* __restrict__ cur) {
    __shared__ int sh[1024];
    int t = threadIdx.x;
    int base = t * 20;
    int local[20];
    int s = 0;
#pragma unroll
    for (int j = 0; j < 20; ++j) {
        int i = base + j;
        int v = (i < N_NODES) ? deg[i] : 0;
        local[j] = v;
        s += v;
    }
    sh[t] = s;
    __syncthreads();
    for (int o = 1; o < 1024; o <<= 1) {
        int v = sh[t];
        int add = (t >= o) ? sh[t - o] : 0;
        __syncthreads();
        sh[t] = v + add;
        __syncthreads();
    }
    int run = (t > 0) ? sh[t - 1] : 0;
#pragma unroll
    for (int j = 0; j < 20; ++j) {
        int i = base + j;
        if (i < N_NODES) {
            off[i] = run;
            cur[i] = run;
            run += local[j];
        }
    }
    if (t == 1023) off[N_NODES] = sh[1023];
}

__global__ void scatter_kernel(const int* __restrict__ src,
                               const int* __restrict__ dst,
                               const float* __restrict__ edge_attr,
                               int* __restrict__ cur,
                               int* __restrict__ perm_src,
                               float* __restrict__ pea) {
    int e = blockIdx.x * blockDim.x + threadIdx.x;
    if (e >= N_EDGES) return;
    int d = dst[e];
    int p = atomicAdd(&cur[d], 1);
    perm_src[p] = src[e];
    const float* ar = edge_attr + (size_t)e * EDIM;
    float* pr = pea + (size_t)p * 8;
#pragma unroll
    for (int j = 0; j < EDIM; ++j) pr[j] = ar[j];
    pr[7] = 0.0f;
}

// ------- one node per wave, 2-deep pipeline (round-4 proven, 75.6 us) --------
// z = (1+eps)*h + sum relu(h[src]+ea); block 0 zeroes the BN stat buffers.
#define MSG_BLOCKS 5000
__global__ __launch_bounds__(256) void msg_kernel(
    const ushort_t* __restrict__ h_bf, ushort_t* __restrict__ z_bf,
    const int* __restrict__ off, const int* __restrict__ perm_src,
    const float* __restrict__ pea,
    const float* __restrict__ edge_W, const float* __restrict__ edge_b,
    const float* __restrict__ eps, int layer,
    float* __restrict__ s1a, float* __restrict__ s2a,
    float* __restrict__ s1b, float* __restrict__ s2b) {
    if (blockIdx.x == 0) {
        for (int d = threadIdx.x; d < ADIM; d += 256) {
            s1a[d] = 0.f; s2a[d] = 0.f; s1b[d] = 0.f; s2b[d] = 0.f;
        }
    }
    int n = (blockIdx.x * 256 + threadIdx.x) >> 6;
    if (n >= N_NODES) return;
    int lane = threadIdx.x & 63;

    float ew[5][7], eb[5];
#pragma unroll
    for (int c = 0; c < 5; ++c) {
        int d = c * 64 + lane;
        bool ok = (d < DIM);
        eb[c] = ok ? edge_b[d] : 0.0f;
#pragma unroll
        for (int j = 0; j < EDIM; ++j)
            ew[c][j] = ok ? edge_W[j * DIM + d] : 0.0f;
    }
    float epsv = 1.0f + eps[layer];

    int p0 = off[n], p1 = off[n + 1];
    float acc[5] = {0.f, 0.f, 0.f, 0.f, 0.f};
    float4 na03, na47;
    float nhv[5];
    int s2i = 0;
    if (p0 < p1) {
        int s1i = perm_src[p0];
        const float* ap = pea + (size_t)p0 * 8;
        na03 = *(const float4*)ap;
        na47 = *(const float4*)(ap + 4);
        const ushort_t* hr = h_bf + (size_t)s1i * ADIM;
#pragma unroll
        for (int c = 0; c < 5; ++c) nhv[c] = bf2f(hr[c * 64 + lane]);
        if (p0 + 1 < p1) s2i = perm_src[p0 + 1];
    }
    for (int p = p0; p < p1; ++p) {
        float4 ca03 = na03, ca47 = na47;
        float chv[5];
#pragma unroll
        for (int c = 0; c < 5; ++c) chv[c] = nhv[c];
        if (p + 1 < p1) {
            const float* ap = pea + (size_t)(p + 1) * 8;
            na03 = *(const float4*)ap;
            na47 = *(const float4*)(ap + 4);
            const ushort_t* hr = h_bf + (size_t)s2i * ADIM;
#pragma unroll
            for (int c = 0; c < 5; ++c) nhv[c] = bf2f(hr[c * 64 + lane]);
            if (p + 2 < p1) s2i = perm_src[p + 2];
        }
#pragma unroll
        for (int c = 0; c < 5; ++c) {
            float ea = eb[c];
            ea += ca03.x * ew[c][0];
            ea += ca03.y * ew[c][1];
            ea += ca03.z * ew[c][2];
            ea += ca03.w * ew[c][3];
            ea += ca47.x * ew[c][4];
            ea += ca47.y * ew[c][5];
            ea += ca47.z * ew[c][6];
            acc[c] += fmaxf(chv[c] + ea, 0.0f);
        }
    }
    const ushort_t* hn = h_bf + (size_t)n * ADIM;
    ushort_t* zr = z_bf + (size_t)n * ADIM;
#pragma unroll
    for (int c = 0; c < 5; ++c) {
        int d = c * 64 + lane;
        float z = epsv * bf2f(hn[d]) + acc[c];
        zr[d] = f2bf(z);
    }
}

// ---------------- bf16 MFMA GEMM + fused BN stats ----------------------------
// Block 128x80, 4 waves (wave tile 32x80), K-step 64, grid 157x4 = 628 blocks.
// BNA=true: A elements transformed relu(bf2f(a)*scale[k]+shift[k]) during
//           staging (scale/shift from raw sums; pad-row garbage row-confined).
// OBF=true: output written as bf16 (Ybf); else f32 (Y).
// Stats (from exact f32 accumulators): per-column sum/sumsq -> gs1/gs2.
__device__ __forceinline__ int swz(int row, int k8) {
    return ((row << 7) + (k8 << 4)) ^ ((row & 7) << 4);
}

template <bool BNA, bool OBF>
__global__ __launch_bounds__(256) void gemm_kernel(
    const ushort_t* __restrict__ A, const ushort_t* __restrict__ Wt,
    float* __restrict__ Y, ushort_t* __restrict__ Ybf,
    const float* __restrict__ in_s1, const float* __restrict__ in_s2,
    const float* __restrict__ bn_g, const float* __restrict__ bn_be,
    float* __restrict__ gs1, float* __restrict__ gs2) {
    __shared__ ushort_t sA[128 * 64];   // 16 KB, swizzled
    __shared__ ushort_t sB[80 * 64];    // 10 KB, swizzled
    __shared__ float sRed[4 * 160];     // stats cross-wave reduce
    __shared__ float s_scale[ADIM], s_shift[ADIM];
    char* sAc = (char*)sA;
    char* sBc = (char*)sB;

    int tid = threadIdx.x;
    int lane = tid & 63;
    int wv = tid >> 6;                  // wave -> 32-row strip
    int row0 = blockIdx.x * 128;
    int col0 = blockIdx.y * 80;
    int l15 = lane & 15, l4 = lane >> 4;

    if (BNA) {
        for (int d = tid; d < ADIM; d += 256) {
            float sc = 0.f, sh = 0.f;
            if (d < DIM) {
                const float invn = 1.0f / (float)N_NODES;
                float mean = in_s1[d] * invn;
                float var = in_s2[d] * invn - mean * mean;
                sc = bn_g[d] * rsqrtf(var + BN_EPS);
                sh = bn_be[d] - mean * sc;
            }
            s_scale[d] = sc;
            s_shift[d] = sh;
        }
        __syncthreads();
    }

    f32x4 acc[2][5];
#pragma unroll
    for (int m = 0; m < 2; ++m)
#pragma unroll
        for (int n = 0; n < 5; ++n) acc[m][n] = (f32x4){0.f, 0.f, 0.f, 0.f};

    for (int kt = 0; kt < 5; ++kt) {
        int k0 = kt * 64;
        // stage A: 128x64 -> 1024 16B chunks, 4/thread
#pragma unroll
        for (int it = 0; it < 4; ++it) {
            int idx = tid + it * 256;
            int row = idx >> 3, k8 = idx & 7;
            const ushort_t* g = A + (size_t)(row0 + row) * ADIM + k0 + k8 * 8;
            uint4 raw = *(const uint4*)g;
            if (!BNA) {
                *(uint4*)(sAc + swz(row, k8)) = raw;
            } else {
                union { ushort_t u[8]; uint4 v; } in, o;
                in.v = raw;
                int kb = k0 + k8 * 8;
#pragma unroll
                for (int j = 0; j < 8; ++j)
                    o.u[j] = f2bf(fmaxf(bf2f(in.u[j]) * s_scale[kb + j] +
                                        s_shift[kb + j], 0.0f));
                *(uint4*)(sAc + swz(row, k8)) = o.v;
            }
        }
        // stage B: 80x64 -> 640 chunks
#pragma unroll
        for (int it = 0; it < 3; ++it) {
            int idx = tid + it * 256;
            if (idx < 640) {
                int row = idx >> 3, k8 = idx & 7;
                const ushort_t* g = Wt + (size_t)(col0 + row) * ADIM + k0 + k8 * 8;
                *(uint4*)(sBc + swz(row, k8)) = *(const uint4*)g;
            }
        }
        __syncthreads();

#pragma unroll
        for (int kk = 0; kk < 2; ++kk) {
            bf16x8 a[2], b[5];
#pragma unroll
            for (int m = 0; m < 2; ++m)
                a[m] = *(const bf16x8*)(sAc + swz(wv * 32 + m * 16 + l15, kk * 4 + l4));
#pragma unroll
            for (int n = 0; n < 5; ++n)
                b[n] = *(const bf16x8*)(sBc + swz(n * 16 + l15, kk * 4 + l4));
#pragma unroll
            for (int m = 0; m < 2; ++m)
#pragma unroll
                for (int n = 0; n < 5; ++n)
                    acc[m][n] = __builtin_amdgcn_mfma_f32_16x16x32_bf16(
                        a[m], b[n], acc[m][n], 0, 0, 0);
        }
        __syncthreads();
    }

    // ---- write output + per-wave column stats (stats from exact f32) ----
#pragma unroll
    for (int n = 0; n < 5; ++n) {
        int col = col0 + n * 16 + l15;
        float s1 = 0.f, s2 = 0.f;
#pragma unroll
        for (int m = 0; m < 2; ++m) {
#pragma unroll
            for (int r = 0; r < 4; ++r) {
                int row = row0 + wv * 32 + m * 16 + l4 * 4 + r;
                float v = acc[m][n][r];
                if (row < N_NODES && col < DIM) {
                    if (OBF) Ybf[(size_t)row * ADIM + col] = f2bf(v);
                    else     Y[(size_t)row * ADIM + col] = v;
                    s1 += v;
                    s2 += v * v;
                }
            }
        }
        s1 += __shfl_xor(s1, 16, 64);
        s1 += __shfl_xor(s1, 32, 64);
        s2 += __shfl_xor(s2, 16, 64);
        s2 += __shfl_xor(s2, 32, 64);
        if (l4 == 0) {
            sRed[wv * 160 + n * 16 + l15] = s1;
            sRed[wv * 160 + 80 + n * 16 + l15] = s2;
        }
    }
    __syncthreads();
    if (tid < 160) {
        float v = sRed[tid] + sRed[160 + tid] + sRed[320 + tid] + sRed[480 + tid];
        int cc = (tid < 80) ? tid : tid - 80;
        int col = col0 + cc;
        if (col < DIM) atomicAdd(((tid < 80) ? gs1 : gs2) + col, v);
    }
}

// ------- h_bf = bf16(relu(BN(y))) with scale/shift computed inline ----------
__global__ void apply_bn_kernel(const float* __restrict__ y,
                                const float* __restrict__ s1,
                                const float* __restrict__ s2,
                                const float* __restrict__ g,
                                const float* __restrict__ be,
                                ushort_t* __restrict__ out_bf) {
    int idx = blockIdx.x * blockDim.x + threadIdx.x;  // 20000*40
    if (idx >= N_NODES * 40) return;
    int n = idx / 40;
    int d0 = (idx - n * 40) * 8;
    const float* yr = y + (size_t)n * ADIM + d0;
    const float invn = 1.0f / (float)N_NODES;
    union { ushort_t u[8]; uint4 v; } o;
#pragma unroll
    for (int j = 0; j < 8; ++j) {
        int d = d0 + j;
        float r = 0.0f;
        if (d < DIM) {
            float mean = s1[d] * invn;
            float var = s2[d] * invn - mean * mean;
            float sc = g[d] * rsqrtf(var + BN_EPS);
            float sh = be[d] - mean * sc;
            r = fmaxf(yr[j] * sc + sh, 0.0f);
        }
        o.u[j] = f2bf(r);
    }
    *(uint4*)(out_bf + (size_t)n * ADIM + d0) = o.v;
}

// ---------------- pooling: sorted batch -> segmented reduction --------------
__device__ __forceinline__ int lbound(const int* __restrict__ batch, int g) {
    int lo = 0, hi = N_NODES;
    while (lo < hi) {
        int mid = (lo + hi) >> 1;
        if (batch[mid] < g) lo = mid + 1; else hi = mid;
    }
    return lo;
}

__global__ void pool_kernel(const ushort_t* __restrict__ h_bf,
                            const int* __restrict__ batch,
                            float* __restrict__ pooled,
                            float* __restrict__ counts) {
    int g = blockIdx.x;
    int chunk = blockIdx.y;   // 0..3
    int d = threadIdx.x;      // 320
    int s = lbound(batch, g);
    int e = lbound(batch, g + 1);
    if (chunk == 0 && d == 0) counts[g] = (float)(e - s);
    if (d >= DIM) return;
    int len = e - s;
    int per = (len + 3) >> 2;
    int r0 = s + chunk * per;
    int r1 = min(r0 + per, e);
    float a = 0.f;
    for (int r = r0; r < r1; ++r) a += bf2f(h_bf[(size_t)r * ADIM + d]);
    if (r1 > r0) atomicAdd(&pooled[(size_t)g * DIM + d], a);
}

// ---------------- MLP head ----------------
__global__ void mlp1_kernel(const float* __restrict__ pooled,
                            const float* __restrict__ counts,
                            const float* __restrict__ Wc1,
                            const float* __restrict__ bc1,
                            float* __restrict__ hidden) {
    int g = blockIdx.x;
    int j = threadIdx.x;  // 192
    if (j >= DHALF) return;
    float inv = 1.0f / fmaxf(counts[g], 1.0f);
    const float* prow = pooled + (size_t)g * DIM;
    float acc = 0.0f;
    for (int k = 0; k < DIM; ++k) acc += prow[k] * Wc1[k * DHALF + j];
    hidden[g * DHALF + j] = fmaxf(acc * inv + bc1[j], 0.0f);
}

__global__ void mlp2_kernel(const float* __restrict__ hidden,
                            const float* __restrict__ Wc2,
                            const float* __restrict__ bc2,
                            float* __restrict__ out) {
    int idx = blockIdx.x * blockDim.x + threadIdx.x;
    if (idx >= NGRAPH * NCLS) return;
    int g = idx / NCLS;
    int c = idx - g * NCLS;
    const float* hrow = hidden + g * DHALF;
    float acc = bc2[c];
    for (int j = 0; j < DHALF; ++j) acc += hrow[j] * Wc2[j * NCLS + c];
    out[idx] = acc;
}

extern "C" void kernel_launch(void* const* d_in, const int* in_sizes, int n_in,
                              void* d_out, int out_size, void* d_ws, size_t ws_size,
                              hipStream_t stream) {
    const int*   x         = (const int*)d_in[0];
    const int*   edge_index= (const int*)d_in[1];
    const float* edge_attr = (const float*)d_in[2];
    const int*   batch     = (const int*)d_in[3];
    const float* node_emb  = (const float*)d_in[4];
    const float* edge_W    = (const float*)d_in[5];
    const float* edge_b    = (const float*)d_in[6];
    const float* eps       = (const float*)d_in[7];
    const float* W1        = (const float*)d_in[8];
    const float* g1        = (const float*)d_in[10];
    const float* be1       = (const float*)d_in[11];
    const float* W2        = (const float*)d_in[12];
    const float* g2        = (const float*)d_in[14];
    const float* be2       = (const float*)d_in[15];
    const float* Wc1       = (const float*)d_in[16];
    const float* bc1       = (const float*)d_in[17];
    const float* Wc2       = (const float*)d_in[18];
    const float* bc2       = (const float*)d_in[19];
    float* out = (float*)d_out;

    const int* src = edge_index;
    const int* dst = edge_index + N_EDGES;

    char* w = (char*)d_ws;
    size_t cur_off = 0;
    auto alloc = [&](size_t bytes) {
        char* p = w + cur_off;
        cur_off += (bytes + 63) & ~(size_t)63;
        return p;
    };
    const size_t AROW = (size_t)ROWS_PAD * ADIM;
    ushort_t* h_bf  = (ushort_t*)alloc(AROW * 2);
    ushort_t* zab   = (ushort_t*)alloc(AROW * 2);
    ushort_t* y1bf  = (ushort_t*)alloc(AROW * 2);   // GEMM1 output (bf16)
    float*    Ybuf  = (float*)alloc(AROW * 4);      // GEMM2 output (f32)
    ushort_t* Wt    = (ushort_t*)alloc((size_t)10 * ADIM * ADIM * 2);
    int*      deg   = (int*)alloc(N_NODES * 4);
    int*      off   = (int*)alloc((N_NODES + 1) * 4);
    int*      curp  = (int*)alloc(N_NODES * 4);
    int*      psrc  = (int*)alloc((size_t)N_EDGES * 4);
    float*    pea   = (float*)alloc((size_t)N_EDGES * 8 * 4);
    float*    s1a   = (float*)alloc(ADIM * 4);
    float*    s2a   = (float*)alloc(ADIM * 4);
    float*    s1b   = (float*)alloc(ADIM * 4);
    float*    s2b   = (float*)alloc(ADIM * 4);
    float*    pooled= (float*)alloc((size_t)NGRAPH * DIM * 4);
    float*    counts= (float*)alloc(NGRAPH * 4);
    float*    hidden= (float*)alloc((size_t)NGRAPH * DHALF * 4);

    // ---- prep ----
    hipMemsetAsync(deg, 0, N_NODES * 4, stream);
    hipMemsetAsync(zab + (size_t)N_NODES * ADIM, 0,
                   (size_t)(ROWS_PAD - N_NODES) * ADIM * 2, stream);

    node_enc_kernel<<<CDIV(N_NODES * 40, 256), 256, 0, stream>>>(x, node_emb, h_bf);
    wt_prep_kernel<<<CDIV(10 * ADIM * ADIM, 256), 256, 0, stream>>>(W1, W2, Wt);
    deg_kernel<<<CDIV(N_EDGES, 256), 256, 0, stream>>>(dst, deg);
    scan_kernel<<<1, 1024, 0, stream>>>(deg, off, curp);
    scatter_kernel<<<CDIV(N_EDGES, 256), 256, 0, stream>>>(src, dst, edge_attr,
                                                           curp, psrc, pea);

    dim3 ggrid(ROWS_PAD / 128, 4);  // 157 x 4

    for (int i = 0; i < N_LAYERS; ++i) {
        // z = (1+eps)*h + agg; block 0 zeroes stat buffers
        msg_kernel<<<MSG_BLOCKS, 256, 0, stream>>>(h_bf, zab, off, psrc, pea,
                                                   edge_W, edge_b, eps, i,
                                                   s1a, s2a, s1b, s2b);
        // Y1(bf16) = z @ W1, stats -> s1a/s2a
        gemm_kernel<false, true><<<ggrid, 256, 0, stream>>>(
            zab, Wt + (size_t)i * ADIM * ADIM, nullptr, y1bf,
            nullptr, nullptr, nullptr, nullptr, s1a, s2a);
        // Y2(f32) = relu(BN1(Y1)) @ W2 (BN fused into staging), stats -> s1b/s2b
        gemm_kernel<true, false><<<ggrid, 256, 0, stream>>>(
            y1bf, Wt + (size_t)(5 + i) * ADIM * ADIM, Ybuf, nullptr,
            s1a, s2a, g1 + i * DIM, be1 + i * DIM, s1b, s2b);
        // h = relu(BN2(Y2))
        apply_bn_kernel<<<CDIV(N_NODES * 40, 256), 256, 0, stream>>>(
            Ybuf, s1b, s2b, g2 + i * DIM, be2 + i * DIM, h_bf);
    }

    hipMemsetAsync(pooled, 0, (size_t)NGRAPH * DIM * 4, stream);
    dim3 pgrid(NGRAPH, 4);
    pool_kernel<<<pgrid, ADIM, 0, stream>>>(h_bf, batch, pooled, counts);
    mlp1_kernel<<<NGRAPH, 192, 0, stream>>>(pooled, counts, Wc1, bc1, hidden);
    mlp2_kernel<<<CDIV(NGRAPH * NCLS, 256), 256, 0, stream>>>(hidden, Wc2, bc2, out);
}

// Round 11
// 705.062 us; speedup vs baseline: 1.7747x; 1.3625x over previous
//
#include <hip/hip_runtime.h>
#include <hip/hip_bf16.h>
#include <stdint.h>

#define N_NODES 20000
#define N_EDGES 320000
#define DIM 300
#define ADIM 320              // padded activation stride (cols 300..319 = 0)
#define ROWS_PAD 20096        // 157 * 128
#define N_LAYERS 5
#define EDIM 7
#define NGRAPH 128
#define NCLS 6
#define DHALF 150
#define BN_EPS 1e-5f

#define CDIV(a, b) (((a) + (b) - 1) / (b))

typedef short bf16x8 __attribute__((ext_vector_type(8)));
typedef float f32x4 __attribute__((ext_vector_type(4)));
typedef unsigned short ushort_t;

__device__ __forceinline__ float bf2f(ushort_t u) {
    union { float f; uint32_t i; } v; v.i = ((uint32_t)u) << 16; return v.f;
}
__device__ __forceinline__ ushort_t f2bf(float f) {
    union { float f; uint32_t i; } v; v.f = f;
    uint32_t x = v.i;
    x += 0x7FFFu + ((x >> 16) & 1u);   // RTN-even (no inf/nan expected)
    return (ushort_t)(x >> 16);
}

// ---------------- node encoder: h_bf[n][d] = bf16(node_emb[x[n]][d]) --------
__global__ void node_enc_kernel(const int* __restrict__ x,
                                const float* __restrict__ node_emb,
                                ushort_t* __restrict__ h_bf) {
    int idx = blockIdx.x * blockDim.x + threadIdx.x;  // 20000*40
    if (idx >= N_NODES * 40) return;
    int n = idx / 40;
    int d0 = (idx - n * 40) * 8;
    const float* src = node_emb + (size_t)x[n] * DIM;
    union { ushort_t u[8]; uint4 v; } o;
#pragma unroll
    for (int j = 0; j < 8; ++j) {
        int d = d0 + j;
        o.u[j] = (d < DIM) ? f2bf(src[d]) : (ushort_t)0;
    }
    *(uint4*)(h_bf + (size_t)n * ADIM + d0) = o.v;
}

// -------- W transpose+convert: Wt[mat][n][k] = bf16(W[k][n]), k fastest -----
__global__ void wt_prep_kernel(const float* __restrict__ W1,
                               const float* __restrict__ W2,
                               ushort_t* __restrict__ Wt) {
    int idx = blockIdx.x * blockDim.x + threadIdx.x;  // 10*320*320
    if (idx >= 10 * ADIM * ADIM) return;
    int mat = idx / (ADIM * ADIM);
    int rem = idx - mat * ADIM * ADIM;
    int n = rem / ADIM;          // output col (row of Wt)
    int k = rem - n * ADIM;      // k fastest -> coalesced writes
    const float* src = (mat < 5) ? (W1 + (size_t)mat * DIM * DIM)
                                 : (W2 + (size_t)(mat - 5) * DIM * DIM);
    float v = (k < DIM && n < DIM) ? src[(size_t)k * DIM + n] : 0.0f;
    Wt[(size_t)mat * ADIM * ADIM + (size_t)n * ADIM + k] = f2bf(v);
}

// ---------------- CSR build ----------------
__global__ void deg_kernel(const int* __restrict__ dst, int* __restrict__ deg) {
    int e = blockIdx.x * blockDim.x + threadIdx.x;
    if (e < N_EDGES) atomicAdd(&deg[dst[e]], 1);
}

__global__ void scan_kernel(const int* __restrict__ deg, int* __restrict__ off,
                            int* __restrict__ cur) {
    __shared__ int sh[1024];
    int t = threadIdx.x;
    int base = t * 20;
    int local[20];
    int s = 0;
#pragma unroll
    for (int j = 0; j < 20; ++j) {
        int i = base + j;
        int v = (i < N_NODES) ? deg[i] : 0;
        local[j] = v;
        s += v;
    }
    sh[t] = s;
    __syncthreads();
    for (int o = 1; o < 1024; o <<= 1) {
        int v = sh[t];
        int add = (t >= o) ? sh[t - o] : 0;
        __syncthreads();
        sh[t] = v + add;
        __syncthreads();
    }
    int run = (t > 0) ? sh[t - 1] : 0;
#pragma unroll
    for (int j = 0; j < 20; ++j) {
        int i = base + j;
        if (i < N_NODES) {
            off[i] = run;
            cur[i] = run;
            run += local[j];
        }
    }
    if (t == 1023) off[N_NODES] = sh[1023];
}

__global__ void scatter_kernel(const int* __restrict__ src,
                               const int* __restrict__ dst,
                               const float* __restrict__ edge_attr,
                               int* __restrict__ cur,
                               int* __restrict__ perm_src,
                               float* __restrict__ pea) {
    int e = blockIdx.x * blockDim.x + threadIdx.x;
    if (e >= N_EDGES) return;
    int d = dst[e];
    int p = atomicAdd(&cur[d], 1);
    perm_src[p] = src[e];
    const float* ar = edge_attr + (size_t)e * EDIM;
    float* pr = pea + (size_t)p * 8;
#pragma unroll
    for (int j = 0; j < EDIM; ++j) pr[j] = ar[j];
    pr[7] = 0.0f;
}

// ------- one node per wave, 2-deep pipeline; BNH: h = relu(BN(y_bf)) inline --
// z = (1+eps)*h + sum relu(h[src]+ea)
#define MSG_BLOCKS 5000
template <bool BNH>
__global__ __launch_bounds__(256) void msg_kernel(
    const ushort_t* __restrict__ hsrc, ushort_t* __restrict__ z_bf,
    const int* __restrict__ off, const int* __restrict__ perm_src,
    const float* __restrict__ pea,
    const float* __restrict__ edge_W, const float* __restrict__ edge_b,
    const float* __restrict__ eps, int layer,
    const float* __restrict__ bs1, const float* __restrict__ bs2,
    const float* __restrict__ bg, const float* __restrict__ bbe) {
    int n = (blockIdx.x * 256 + threadIdx.x) >> 6;
    if (n >= N_NODES) return;
    int lane = threadIdx.x & 63;

    float ew[5][7], eb[5], sc[5], sh[5];
#pragma unroll
    for (int c = 0; c < 5; ++c) {
        int d = c * 64 + lane;
        bool ok = (d < DIM);
        eb[c] = ok ? edge_b[d] : 0.0f;
#pragma unroll
        for (int j = 0; j < EDIM; ++j)
            ew[c][j] = ok ? edge_W[j * DIM + d] : 0.0f;
        if (BNH) {
            float s = 0.f, t = 0.f;
            if (ok) {
                const float invn = 1.0f / (float)N_NODES;
                float mean = bs1[d] * invn;
                float var = bs2[d] * invn - mean * mean;
                s = bg[d] * rsqrtf(var + BN_EPS);
                t = bbe[d] - mean * s;
            }
            sc[c] = s;
            sh[c] = t;
        }
    }
    float epsv = 1.0f + eps[layer];

    int p0 = off[n], p1 = off[n + 1];
    float acc[5] = {0.f, 0.f, 0.f, 0.f, 0.f};
    float4 na03, na47;
    float nhv[5];
    int s2i = 0;
    if (p0 < p1) {
        int s1i = perm_src[p0];
        const float* ap = pea + (size_t)p0 * 8;
        na03 = *(const float4*)ap;
        na47 = *(const float4*)(ap + 4);
        const ushort_t* hr = hsrc + (size_t)s1i * ADIM;
#pragma unroll
        for (int c = 0; c < 5; ++c) nhv[c] = bf2f(hr[c * 64 + lane]);
        if (p0 + 1 < p1) s2i = perm_src[p0 + 1];
    }
    for (int p = p0; p < p1; ++p) {
        float4 ca03 = na03, ca47 = na47;
        float chv[5];
#pragma unroll
        for (int c = 0; c < 5; ++c) chv[c] = nhv[c];
        if (p + 1 < p1) {
            const float* ap = pea + (size_t)(p + 1) * 8;
            na03 = *(const float4*)ap;
            na47 = *(const float4*)(ap + 4);
            const ushort_t* hr = hsrc + (size_t)s2i * ADIM;
#pragma unroll
            for (int c = 0; c < 5; ++c) nhv[c] = bf2f(hr[c * 64 + lane]);
            if (p + 2 < p1) s2i = perm_src[p + 2];
        }
#pragma unroll
        for (int c = 0; c < 5; ++c) {
            float hv = BNH ? fmaxf(chv[c] * sc[c] + sh[c], 0.0f) : chv[c];
            float ea = eb[c];
            ea += ca03.x * ew[c][0];
            ea += ca03.y * ew[c][1];
            ea += ca03.z * ew[c][2];
            ea += ca03.w * ew[c][3];
            ea += ca47.x * ew[c][4];
            ea += ca47.y * ew[c][5];
            ea += ca47.z * ew[c][6];
            acc[c] += fmaxf(hv + ea, 0.0f);
        }
    }
    const ushort_t* hn = hsrc + (size_t)n * ADIM;
    ushort_t* zr = z_bf + (size_t)n * ADIM;
#pragma unroll
    for (int c = 0; c < 5; ++c) {
        int d = c * 64 + lane;
        float hv = bf2f(hn[d]);
        if (BNH) hv = fmaxf(hv * sc[c] + sh[c], 0.0f);
        zr[d] = f2bf(epsv * hv + acc[c]);
    }
}

// ---------------- bf16 MFMA GEMM + fused BN stats ----------------------------
// Block 128x80, 4 waves (wave tile 32x80), K-step 64, grid 157x4 = 628 blocks.
// BNA=true: A elements transformed relu(bf2f(a)*scale[k]+shift[k]) during
//           staging (scale/shift from raw sums; pad-row garbage row-confined).
// Output bf16 (rows<20000, cols<300); stats from exact f32 accumulators.
__device__ __forceinline__ int swz(int row, int k8) {
    return ((row << 7) + (k8 << 4)) ^ ((row & 7) << 4);
}

template <bool BNA>
__global__ __launch_bounds__(256) void gemm_kernel(
    const ushort_t* __restrict__ A, const ushort_t* __restrict__ Wt,
    ushort_t* __restrict__ Ybf,
    const float* __restrict__ in_s1, const float* __restrict__ in_s2,
    const float* __restrict__ bn_g, const float* __restrict__ bn_be,
    float* __restrict__ gs1, float* __restrict__ gs2) {
    __shared__ ushort_t sA[128 * 64];   // 16 KB, swizzled
    __shared__ ushort_t sB[80 * 64];    // 10 KB, swizzled
    __shared__ float sRed[4 * 160];     // stats cross-wave reduce
    __shared__ float s_scale[ADIM], s_shift[ADIM];
    char* sAc = (char*)sA;
    char* sBc = (char*)sB;

    int tid = threadIdx.x;
    int lane = tid & 63;
    int wv = tid >> 6;                  // wave -> 32-row strip
    int row0 = blockIdx.x * 128;
    int col0 = blockIdx.y * 80;
    int l15 = lane & 15, l4 = lane >> 4;

    if (BNA) {
        for (int d = tid; d < ADIM; d += 256) {
            float sc = 0.f, sh = 0.f;
            if (d < DIM) {
                const float invn = 1.0f / (float)N_NODES;
                float mean = in_s1[d] * invn;
                float var = in_s2[d] * invn - mean * mean;
                sc = bn_g[d] * rsqrtf(var + BN_EPS);
                sh = bn_be[d] - mean * sc;
            }
            s_scale[d] = sc;
            s_shift[d] = sh;
        }
        __syncthreads();
    }

    f32x4 acc[2][5];
#pragma unroll
    for (int m = 0; m < 2; ++m)
#pragma unroll
        for (int n = 0; n < 5; ++n) acc[m][n] = (f32x4){0.f, 0.f, 0.f, 0.f};

    for (int kt = 0; kt < 5; ++kt) {
        int k0 = kt * 64;
        // stage A: 128x64 -> 1024 16B chunks, 4/thread
#pragma unroll
        for (int it = 0; it < 4; ++it) {
            int idx = tid + it * 256;
            int row = idx >> 3, k8 = idx & 7;
            const ushort_t* g = A + (size_t)(row0 + row) * ADIM + k0 + k8 * 8;
            uint4 raw = *(const uint4*)g;
            if (!BNA) {
                *(uint4*)(sAc + swz(row, k8)) = raw;
            } else {
                union { ushort_t u[8]; uint4 v; } in, o;
                in.v = raw;
                int kb = k0 + k8 * 8;
#pragma unroll
                for (int j = 0; j < 8; ++j)
                    o.u[j] = f2bf(fmaxf(bf2f(in.u[j]) * s_scale[kb + j] +
                                        s_shift[kb + j], 0.0f));
                *(uint4*)(sAc + swz(row, k8)) = o.v;
            }
        }
        // stage B: 80x64 -> 640 chunks
#pragma unroll
        for (int it = 0; it < 3; ++it) {
            int idx = tid + it * 256;
            if (idx < 640) {
                int row = idx >> 3, k8 = idx & 7;
                const ushort_t* g = Wt + (size_t)(col0 + row) * ADIM + k0 + k8 * 8;
                *(uint4*)(sBc + swz(row, k8)) = *(const uint4*)g;
            }
        }
        __syncthreads();

#pragma unroll
        for (int kk = 0; kk < 2; ++kk) {
            bf16x8 a[2], b[5];
#pragma unroll
            for (int m = 0; m < 2; ++m)
                a[m] = *(const bf16x8*)(sAc + swz(wv * 32 + m * 16 + l15, kk * 4 + l4));
#pragma unroll
            for (int n = 0; n < 5; ++n)
                b[n] = *(const bf16x8*)(sBc + swz(n * 16 + l15, kk * 4 + l4));
#pragma unroll
            for (int m = 0; m < 2; ++m)
#pragma unroll
                for (int n = 0; n < 5; ++n)
                    acc[m][n] = __builtin_amdgcn_mfma_f32_16x16x32_bf16(
                        a[m], b[n], acc[m][n], 0, 0, 0);
        }
        __syncthreads();
    }

    // ---- write bf16 output + per-wave column stats (stats from exact f32) --
#pragma unroll
    for (int n = 0; n < 5; ++n) {
        int col = col0 + n * 16 + l15;
        float s1 = 0.f, s2 = 0.f;
#pragma unroll
        for (int m = 0; m < 2; ++m) {
#pragma unroll
            for (int r = 0; r < 4; ++r) {
                int row = row0 + wv * 32 + m * 16 + l4 * 4 + r;
                float v = acc[m][n][r];
                if (row < N_NODES && col < DIM) {
                    Ybf[(size_t)row * ADIM + col] = f2bf(v);
                    s1 += v;
                    s2 += v * v;
                }
            }
        }
        s1 += __shfl_xor(s1, 16, 64);
        s1 += __shfl_xor(s1, 32, 64);
        s2 += __shfl_xor(s2, 16, 64);
        s2 += __shfl_xor(s2, 32, 64);
        if (l4 == 0) {
            sRed[wv * 160 + n * 16 + l15] = s1;
            sRed[wv * 160 + 80 + n * 16 + l15] = s2;
        }
    }
    __syncthreads();
    if (tid < 160) {
        float v = sRed[tid] + sRed[160 + tid] + sRed[320 + tid] + sRed[480 + tid];
        int cc = (tid < 80) ? tid : tid - 80;
        int col = col0 + cc;
        if (col < DIM) atomicAdd(((tid < 80) ? gs1 : gs2) + col, v);
    }
}

// -------- pooling: sorted batch -> segmented reduction, BN2+relu inline -----
__device__ __forceinline__ int lbound(const int* __restrict__ batch, int g) {
    int lo = 0, hi = N_NODES;
    while (lo < hi) {
        int mid = (lo + hi) >> 1;
        if (batch[mid] < g) lo = mid + 1; else hi = mid;
    }
    return lo;
}

__global__ void pool_kernel(const ushort_t* __restrict__ y_bf,
                            const int* __restrict__ batch,
                            float* __restrict__ pooled,
                            float* __restrict__ counts,
                            const float* __restrict__ bs1,
                            const float* __restrict__ bs2,
                            const float* __restrict__ bg,
                            const float* __restrict__ bbe) {
    int g = blockIdx.x;
    int chunk = blockIdx.y;   // 0..3
    int d = threadIdx.x;      // 320
    int s = lbound(batch, g);
    int e = lbound(batch, g + 1);
    if (chunk == 0 && d == 0) counts[g] = (float)(e - s);
    if (d >= DIM) return;
    const float invn = 1.0f / (float)N_NODES;
    float mean = bs1[d] * invn;
    float var = bs2[d] * invn - mean * mean;
    float sc = bg[d] * rsqrtf(var + BN_EPS);
    float sh = bbe[d] - mean * sc;
    int len = e - s;
    int per = (len + 3) >> 2;
    int r0 = s + chunk * per;
    int r1 = min(r0 + per, e);
    float a = 0.f;
    for (int r = r0; r < r1; ++r)
        a += fmaxf(bf2f(y_bf[(size_t)r * ADIM + d]) * sc + sh, 0.0f);
    if (r1 > r0) atomicAdd(&pooled[(size_t)g * DIM + d], a);
}

// ---------------- MLP head ----------------
__global__ void mlp1_kernel(const float* __restrict__ pooled,
                            const float* __restrict__ counts,
                            const float* __restrict__ Wc1,
                            const float* __restrict__ bc1,
                            float* __restrict__ hidden) {
    int g = blockIdx.x;
    int j = threadIdx.x;  // 192
    if (j >= DHALF) return;
    float inv = 1.0f / fmaxf(counts[g], 1.0f);
    const float* prow = pooled + (size_t)g * DIM;
    float acc = 0.0f;
    for (int k = 0; k < DIM; ++k) acc += prow[k] * Wc1[k * DHALF + j];
    hidden[g * DHALF + j] = fmaxf(acc * inv + bc1[j], 0.0f);
}

__global__ void mlp2_kernel(const float* __restrict__ hidden,
                            const float* __restrict__ Wc2,
                            const float* __restrict__ bc2,
                            float* __restrict__ out) {
    int idx = blockIdx.x * blockDim.x + threadIdx.x;
    if (idx >= NGRAPH * NCLS) return;
    int g = idx / NCLS;
    int c = idx - g * NCLS;
    const float* hrow = hidden + g * DHALF;
    float acc = bc2[c];
    for (int j = 0; j < DHALF; ++j) acc += hrow[j] * Wc2[j * NCLS + c];
    out[idx] = acc;
}

extern "C" void kernel_launch(void* const* d_in, const int* in_sizes, int n_in,
                              void* d_out, int out_size, void* d_ws, size_t ws_size,
                              hipStream_t stream) {
    const int*   x         = (const int*)d_in[0];
    const int*   edge_index= (const int*)d_in[1];
    const float* edge_attr = (const float*)d_in[2];
    const int*   batch     = (const int*)d_in[3];
    const float* node_emb  = (const float*)d_in[4];
    const float* edge_W    = (const float*)d_in[5];
    const float* edge_b    = (const float*)d_in[6];
    const float* eps       = (const float*)d_in[7];
    const float* W1        = (const float*)d_in[8];
    const float* g1        = (const float*)d_in[10];
    const float* be1       = (const float*)d_in[11];
    const float* W2        = (const float*)d_in[12];
    const float* g2        = (const float*)d_in[14];
    const float* be2       = (const float*)d_in[15];
    const float* Wc1       = (const float*)d_in[16];
    const float* bc1       = (const float*)d_in[17];
    const float* Wc2       = (const float*)d_in[18];
    const float* bc2       = (const float*)d_in[19];
    float* out = (float*)d_out;

    const int* src = edge_index;
    const int* dst = edge_index + N_EDGES;

    char* w = (char*)d_ws;
    size_t cur_off = 0;
    auto alloc = [&](size_t bytes) {
        char* p = w + cur_off;
        cur_off += (bytes + 63) & ~(size_t)63;
        return p;
    };
    const size_t AROW = (size_t)ROWS_PAD * ADIM;
    ushort_t* h_bf  = (ushort_t*)alloc(AROW * 2);   // layer-0 input
    ushort_t* zab   = (ushort_t*)alloc(AROW * 2);   // z
    ushort_t* y1bf  = (ushort_t*)alloc(AROW * 2);   // GEMM1 output
    ushort_t* y2bf  = (ushort_t*)alloc(AROW * 2);   // GEMM2 output (pre-BN2)
    ushort_t* Wt    = (ushort_t*)alloc((size_t)10 * ADIM * ADIM * 2);
    int*      deg   = (int*)alloc(N_NODES * 4);
    int*      off   = (int*)alloc((N_NODES + 1) * 4);
    int*      curp  = (int*)alloc(N_NODES * 4);
    int*      psrc  = (int*)alloc((size_t)N_EDGES * 4);
    float*    pea   = (float*)alloc((size_t)N_EDGES * 8 * 4);
    float*    sbuf  = (float*)alloc((size_t)N_LAYERS * 4 * ADIM * 4); // [L][4][ADIM]
    float*    pooled= (float*)alloc((size_t)NGRAPH * DIM * 4);
    float*    counts= (float*)alloc(NGRAPH * 4);
    float*    hidden= (float*)alloc((size_t)NGRAPH * DHALF * 4);

    auto sa1 = [&](int i) { return sbuf + ((size_t)i * 4 + 0) * ADIM; };
    auto sa2 = [&](int i) { return sbuf + ((size_t)i * 4 + 1) * ADIM; };
    auto sb1 = [&](int i) { return sbuf + ((size_t)i * 4 + 2) * ADIM; };
    auto sb2 = [&](int i) { return sbuf + ((size_t)i * 4 + 3) * ADIM; };

    // ---- prep ----
    hipMemsetAsync(deg, 0, N_NODES * 4, stream);
    hipMemsetAsync(zab + (size_t)N_NODES * ADIM, 0,
                   (size_t)(ROWS_PAD - N_NODES) * ADIM * 2, stream);
    hipMemsetAsync(sbuf, 0, (size_t)N_LAYERS * 4 * ADIM * 4, stream);

    node_enc_kernel<<<CDIV(N_NODES * 40, 256), 256, 0, stream>>>(x, node_emb, h_bf);
    wt_prep_kernel<<<CDIV(10 * ADIM * ADIM, 256), 256, 0, stream>>>(W1, W2, Wt);
    deg_kernel<<<CDIV(N_EDGES, 256), 256, 0, stream>>>(dst, deg);
    scan_kernel<<<1, 1024, 0, stream>>>(deg, off, curp);
    scatter_kernel<<<CDIV(N_EDGES, 256), 256, 0, stream>>>(src, dst, edge_attr,
                                                           curp, psrc, pea);

    dim3 ggrid(ROWS_PAD / 128, 4);  // 157 x 4

    for (int i = 0; i < N_LAYERS; ++i) {
        // z = (1+eps)*h + agg, h = relu(BN2(y2_{i-1})) inline for i>0
        if (i == 0)
            msg_kernel<false><<<MSG_BLOCKS, 256, 0, stream>>>(
                h_bf, zab, off, psrc, pea, edge_W, edge_b, eps, i,
                nullptr, nullptr, nullptr, nullptr);
        else
            msg_kernel<true><<<MSG_BLOCKS, 256, 0, stream>>>(
                y2bf, zab, off, psrc, pea, edge_W, edge_b, eps, i,
                sb1(i - 1), sb2(i - 1), g2 + (i - 1) * DIM, be2 + (i - 1) * DIM);
        // y1 = z @ W1, stats -> sa(i)
        gemm_kernel<false><<<ggrid, 256, 0, stream>>>(
            zab, Wt + (size_t)i * ADIM * ADIM, y1bf,
            nullptr, nullptr, nullptr, nullptr, sa1(i), sa2(i));
        // y2 = relu(BN1(y1)) @ W2 (BN1 fused into staging), stats -> sb(i)
        gemm_kernel<true><<<ggrid, 256, 0, stream>>>(
            y1bf, Wt + (size_t)(5 + i) * ADIM * ADIM, y2bf,
            sa1(i), sa2(i), g1 + i * DIM, be1 + i * DIM, sb1(i), sb2(i));
    }

    hipMemsetAsync(pooled, 0, (size_t)NGRAPH * DIM * 4, stream);
    dim3 pgrid(NGRAPH, 4);
    pool_kernel<<<pgrid, ADIM, 0, stream>>>(y2bf, batch, pooled, counts,
                                            sb1(N_LAYERS - 1), sb2(N_LAYERS - 1),
                                            g2 + (N_LAYERS - 1) * DIM,
                                            be2 + (N_LAYERS - 1) * DIM);
    mlp1_kernel<<<NGRAPH, 192, 0, stream>>>(pooled, counts, Wc1, bc1, hidden);
    mlp2_kernel<<<CDIV(NGRAPH * NCLS, 256), 256, 0, stream>>>(hidden, Wc2, bc2, out);
}

// Round 12
// 683.502 us; speedup vs baseline: 1.8307x; 1.0315x over previous
//
#include <hip/hip_runtime.h>
#include <hip/hip_bf16.h>
#include <stdint.h>

#define N_NODES 20000
#define N_EDGES 320000
#define DIM 300
#define ADIM 320              // padded activation stride (cols 300..319 = 0)
#define ROWS_PAD 20480        // 160 * 128  (160 row-blocks = 8 XCDs x 20)
#define N_LAYERS 5
#define EDIM 7
#define NGRAPH 128
#define NCLS 6
#define DHALF 150
#define BN_EPS 1e-5f

#define CDIV(a, b) (((a) + (b) - 1) / (b))

typedef short bf16x8 __attribute__((ext_vector_type(8)));
typedef float f32x4 __attribute__((ext_vector_type(4)));
typedef unsigned short ushort_t;

__device__ __forceinline__ float bf2f(ushort_t u) {
    union { float f; uint32_t i; } v; v.i = ((uint32_t)u) << 16; return v.f;
}
__device__ __forceinline__ ushort_t f2bf(float f) {
    union { float f; uint32_t i; } v; v.f = f;
    uint32_t x = v.i;
    x += 0x7FFFu + ((x >> 16) & 1u);   // RTN-even (no inf/nan expected)
    return (ushort_t)(x >> 16);
}

// ---------------- node encoder: h_bf[n][d] = bf16(node_emb[x[n]][d]) --------
__global__ void node_enc_kernel(const int* __restrict__ x,
                                const float* __restrict__ node_emb,
                                ushort_t* __restrict__ h_bf) {
    int idx = blockIdx.x * blockDim.x + threadIdx.x;  // 20000*40
    if (idx >= N_NODES * 40) return;
    int n = idx / 40;
    int d0 = (idx - n * 40) * 8;
    const float* src = node_emb + (size_t)x[n] * DIM;
    union { ushort_t u[8]; uint4 v; } o;
#pragma unroll
    for (int j = 0; j < 8; ++j) {
        int d = d0 + j;
        o.u[j] = (d < DIM) ? f2bf(src[d]) : (ushort_t)0;
    }
    *(uint4*)(h_bf + (size_t)n * ADIM + d0) = o.v;
}

// -------- W transpose+convert: Wt[mat][n][k] = bf16(W[k][n]), k fastest -----
__global__ void wt_prep_kernel(const float* __restrict__ W1,
                               const float* __restrict__ W2,
                               ushort_t* __restrict__ Wt) {
    int idx = blockIdx.x * blockDim.x + threadIdx.x;  // 10*320*320
    if (idx >= 10 * ADIM * ADIM) return;
    int mat = idx / (ADIM * ADIM);
    int rem = idx - mat * ADIM * ADIM;
    int n = rem / ADIM;          // output col (row of Wt)
    int k = rem - n * ADIM;      // k fastest -> coalesced writes
    const float* src = (mat < 5) ? (W1 + (size_t)mat * DIM * DIM)
                                 : (W2 + (size_t)(mat - 5) * DIM * DIM);
    float v = (k < DIM && n < DIM) ? src[(size_t)k * DIM + n] : 0.0f;
    Wt[(size_t)mat * ADIM * ADIM + (size_t)n * ADIM + k] = f2bf(v);
}

// ---------------- CSR build ----------------
__global__ void deg_kernel(const int* __restrict__ dst, int* __restrict__ deg) {
    int e = blockIdx.x * blockDim.x + threadIdx.x;
    if (e < N_EDGES) atomicAdd(&deg[dst[e]], 1);
}

__global__ void scan_kernel(const int* __restrict__ deg, int* __restrict__ off,
                            int* __restrict__ cur) {
    __shared__ int sh[1024];
    int t = threadIdx.x;
    int base = t * 20;
    int local[20];
    int s = 0;
#pragma unroll
    for (int j = 0; j < 20; ++j) {
        int i = base + j;
        int v = (i < N_NODES) ? deg[i] : 0;
        local[j] = v;
        s += v;
    }
    sh[t] = s;
    __syncthreads();
    for (int o = 1; o < 1024; o <<= 1) {
        int v = sh[t];
        int add = (t >= o) ? sh[t - o] : 0;
        __syncthreads();
        sh[t] = v + add;
        __syncthreads();
    }
    int run = (t > 0) ? sh[t - 1] : 0;
#pragma unroll
    for (int j = 0; j < 20; ++j) {
        int i = base + j;
        if (i < N_NODES) {
            off[i] = run;
            cur[i] = run;
            run += local[j];
        }
    }
    if (t == 1023) off[N_NODES] = sh[1023];
}

__global__ void scatter_kernel(const int* __restrict__ src,
                               const int* __restrict__ dst,
                               const float* __restrict__ edge_attr,
                               int* __restrict__ cur,
                               int* __restrict__ perm_src,
                               float* __restrict__ pea) {
    int e = blockIdx.x * blockDim.x + threadIdx.x;
    if (e >= N_EDGES) return;
    int d = dst[e];
    int p = atomicAdd(&cur[d], 1);
    perm_src[p] = src[e];
    const float* ar = edge_attr + (size_t)e * EDIM;
    float* pr = pea + (size_t)p * 8;
#pragma unroll
    for (int j = 0; j < EDIM; ++j) pr[j] = ar[j];
    pr[7] = 0.0f;
}

// ------- one node per wave, 2-deep pipeline; BNH: h = relu(BN(y_bf)) inline --
// z = (1+eps)*h + sum relu(h[src]+ea)
#define MSG_BLOCKS 5000
template <bool BNH>
__global__ __launch_bounds__(256) void msg_kernel(
    const ushort_t* __restrict__ hsrc, ushort_t* __restrict__ z_bf,
    const int* __restrict__ off, const int* __restrict__ perm_src,
    const float* __restrict__ pea,
    const float* __restrict__ edge_W, const float* __restrict__ edge_b,
    const float* __restrict__ eps, int layer,
    const float* __restrict__ bs1, const float* __restrict__ bs2,
    const float* __restrict__ bg, const float* __restrict__ bbe) {
    int n = (blockIdx.x * 256 + threadIdx.x) >> 6;
    if (n >= N_NODES) return;
    int lane = threadIdx.x & 63;

    float ew[5][7], eb[5], sc[5], sh[5];
#pragma unroll
    for (int c = 0; c < 5; ++c) {
        int d = c * 64 + lane;
        bool ok = (d < DIM);
        eb[c] = ok ? edge_b[d] : 0.0f;
#pragma unroll
        for (int j = 0; j < EDIM; ++j)
            ew[c][j] = ok ? edge_W[j * DIM + d] : 0.0f;
        if (BNH) {
            float s = 0.f, t = 0.f;
            if (ok) {
                const float invn = 1.0f / (float)N_NODES;
                float mean = bs1[d] * invn;
                float var = bs2[d] * invn - mean * mean;
                s = bg[d] * rsqrtf(var + BN_EPS);
                t = bbe[d] - mean * s;
            }
            sc[c] = s;
            sh[c] = t;
        }
    }
    float epsv = 1.0f + eps[layer];

    int p0 = off[n], p1 = off[n + 1];
    float acc[5] = {0.f, 0.f, 0.f, 0.f, 0.f};
    float4 na03, na47;
    float nhv[5];
    int s2i = 0;
    if (p0 < p1) {
        int s1i = perm_src[p0];
        const float* ap = pea + (size_t)p0 * 8;
        na03 = *(const float4*)ap;
        na47 = *(const float4*)(ap + 4);
        const ushort_t* hr = hsrc + (size_t)s1i * ADIM;
#pragma unroll
        for (int c = 0; c < 5; ++c) nhv[c] = bf2f(hr[c * 64 + lane]);
        if (p0 + 1 < p1) s2i = perm_src[p0 + 1];
    }
    for (int p = p0; p < p1; ++p) {
        float4 ca03 = na03, ca47 = na47;
        float chv[5];
#pragma unroll
        for (int c = 0; c < 5; ++c) chv[c] = nhv[c];
        if (p + 1 < p1) {
            const float* ap = pea + (size_t)(p + 1) * 8;
            na03 = *(const float4*)ap;
            na47 = *(const float4*)(ap + 4);
            const ushort_t* hr = hsrc + (size_t)s2i * ADIM;
#pragma unroll
            for (int c = 0; c < 5; ++c) nhv[c] = bf2f(hr[c * 64 + lane]);
            if (p + 2 < p1) s2i = perm_src[p + 2];
        }
#pragma unroll
        for (int c = 0; c < 5; ++c) {
            float hv = BNH ? fmaxf(chv[c] * sc[c] + sh[c], 0.0f) : chv[c];
            float ea = eb[c];
            ea += ca03.x * ew[c][0];
            ea += ca03.y * ew[c][1];
            ea += ca03.z * ew[c][2];
            ea += ca03.w * ew[c][3];
            ea += ca47.x * ew[c][4];
            ea += ca47.y * ew[c][5];
            ea += ca47.z * ew[c][6];
            acc[c] += fmaxf(hv + ea, 0.0f);
        }
    }
    const ushort_t* hn = hsrc + (size_t)n * ADIM;
    ushort_t* zr = z_bf + (size_t)n * ADIM;
#pragma unroll
    for (int c = 0; c < 5; ++c) {
        int d = c * 64 + lane;
        float hv = bf2f(hn[d]);
        if (BNH) hv = fmaxf(hv * sc[c] + sh[c], 0.0f);
        zr[d] = f2bf(epsv * hv + acc[c]);
    }
}

// ---------------- bf16 MFMA GEMM + fused BN stats ----------------------------
// 640 blocks 1D, XCD-clustered: the 4 col-tiles of one 128-row block map to
// consecutive slots on ONE XCD (wgid%8 round-robin heuristic) -> A panel is
// fetched into that XCD's L2 once and reused 4x.
// BNA=true: A transformed relu(bf2f(a)*scale[k]+shift[k]) during staging.
// Output bf16 (rows<20000, cols<300); stats from exact f32 accumulators.
__device__ __forceinline__ int swz(int row, int k8) {
    return ((row << 7) + (k8 << 4)) ^ ((row & 7) << 4);
}

template <bool BNA>
__global__ __launch_bounds__(256) void gemm_kernel(
    const ushort_t* __restrict__ A, const ushort_t* __restrict__ Wt,
    ushort_t* __restrict__ Ybf,
    const float* __restrict__ in_s1, const float* __restrict__ in_s2,
    const float* __restrict__ bn_g, const float* __restrict__ bn_be,
    float* __restrict__ gs1, float* __restrict__ gs2) {
    __shared__ ushort_t sA[128 * 64];   // 16 KB, swizzled
    __shared__ ushort_t sB[80 * 64];    // 10 KB, swizzled
    __shared__ float sRed[4 * 160];     // stats cross-wave reduce
    __shared__ float s_scale[ADIM], s_shift[ADIM];
    char* sAc = (char*)sA;
    char* sBc = (char*)sB;

    int tid = threadIdx.x;
    int lane = tid & 63;
    int wv = tid >> 6;                  // wave -> 32-row strip
    // XCD-clustered mapping: xcd = wgid%8 owns row-blocks [xcd*20, xcd*20+20)
    int wgid = blockIdx.x;              // 0..639
    int xcd = wgid & 7, slot = wgid >> 3;        // slot 0..79
    int rb = xcd * 20 + (slot >> 2);             // row-block 0..159
    int ct = slot & 3;                           // col-tile 0..3
    int row0 = rb * 128;
    int col0 = ct * 80;
    int l15 = lane & 15, l4 = lane >> 4;

    if (BNA) {
        for (int d = tid; d < ADIM; d += 256) {
            float sc = 0.f, sh = 0.f;
            if (d < DIM) {
                const float invn = 1.0f / (float)N_NODES;
                float mean = in_s1[d] * invn;
                float var = in_s2[d] * invn - mean * mean;
                sc = bn_g[d] * rsqrtf(var + BN_EPS);
                sh = bn_be[d] - mean * sc;
            }
            s_scale[d] = sc;
            s_shift[d] = sh;
        }
        __syncthreads();
    }

    f32x4 acc[2][5];
#pragma unroll
    for (int m = 0; m < 2; ++m)
#pragma unroll
        for (int n = 0; n < 5; ++n) acc[m][n] = (f32x4){0.f, 0.f, 0.f, 0.f};

    for (int kt = 0; kt < 5; ++kt) {
        int k0 = kt * 64;
        // stage A: 128x64 -> 1024 16B chunks, 4/thread
#pragma unroll
        for (int it = 0; it < 4; ++it) {
            int idx = tid + it * 256;
            int row = idx >> 3, k8 = idx & 7;
            const ushort_t* g = A + (size_t)(row0 + row) * ADIM + k0 + k8 * 8;
            uint4 raw = *(const uint4*)g;
            if (!BNA) {
                *(uint4*)(sAc + swz(row, k8)) = raw;
            } else {
                union { ushort_t u[8]; uint4 v; } in, o;
                in.v = raw;
                int kb = k0 + k8 * 8;
#pragma unroll
                for (int j = 0; j < 8; ++j)
                    o.u[j] = f2bf(fmaxf(bf2f(in.u[j]) * s_scale[kb + j] +
                                        s_shift[kb + j], 0.0f));
                *(uint4*)(sAc + swz(row, k8)) = o.v;
            }
        }
        // stage B: 80x64 -> 640 chunks
#pragma unroll
        for (int it = 0; it < 3; ++it) {
            int idx = tid + it * 256;
            if (idx < 640) {
                int row = idx >> 3, k8 = idx & 7;
                const ushort_t* g = Wt + (size_t)(col0 + row) * ADIM + k0 + k8 * 8;
                *(uint4*)(sBc + swz(row, k8)) = *(const uint4*)g;
            }
        }
        __syncthreads();

#pragma unroll
        for (int kk = 0; kk < 2; ++kk) {
            bf16x8 a[2], b[5];
#pragma unroll
            for (int m = 0; m < 2; ++m)
                a[m] = *(const bf16x8*)(sAc + swz(wv * 32 + m * 16 + l15, kk * 4 + l4));
#pragma unroll
            for (int n = 0; n < 5; ++n)
                b[n] = *(const bf16x8*)(sBc + swz(n * 16 + l15, kk * 4 + l4));
#pragma unroll
            for (int m = 0; m < 2; ++m)
#pragma unroll
                for (int n = 0; n < 5; ++n)
                    acc[m][n] = __builtin_amdgcn_mfma_f32_16x16x32_bf16(
                        a[m], b[n], acc[m][n], 0, 0, 0);
        }
        __syncthreads();
    }

    // ---- write bf16 output + per-wave column stats (stats from exact f32) --
#pragma unroll
    for (int n = 0; n < 5; ++n) {
        int col = col0 + n * 16 + l15;
        float s1 = 0.f, s2 = 0.f;
#pragma unroll
        for (int m = 0; m < 2; ++m) {
#pragma unroll
            for (int r = 0; r < 4; ++r) {
                int row = row0 + wv * 32 + m * 16 + l4 * 4 + r;
                float v = acc[m][n][r];
                if (row < N_NODES && col < DIM) {
                    Ybf[(size_t)row * ADIM + col] = f2bf(v);
                    s1 += v;
                    s2 += v * v;
                }
            }
        }
        s1 += __shfl_xor(s1, 16, 64);
        s1 += __shfl_xor(s1, 32, 64);
        s2 += __shfl_xor(s2, 16, 64);
        s2 += __shfl_xor(s2, 32, 64);
        if (l4 == 0) {
            sRed[wv * 160 + n * 16 + l15] = s1;
            sRed[wv * 160 + 80 + n * 16 + l15] = s2;
        }
    }
    __syncthreads();
    if (tid < 160) {
        float v = sRed[tid] + sRed[160 + tid] + sRed[320 + tid] + sRed[480 + tid];
        int cc = (tid < 80) ? tid : tid - 80;
        int col = col0 + cc;
        if (col < DIM) atomicAdd(((tid < 80) ? gs1 : gs2) + col, v);
    }
}

// -------- pooling: sorted batch -> segmented reduction, BN2+relu inline -----
__device__ __forceinline__ int lbound(const int* __restrict__ batch, int g) {
    int lo = 0, hi = N_NODES;
    while (lo < hi) {
        int mid = (lo + hi) >> 1;
        if (batch[mid] < g) lo = mid + 1; else hi = mid;
    }
    return lo;
}

__global__ void pool_kernel(const ushort_t* __restrict__ y_bf,
                            const int* __restrict__ batch,
                            float* __restrict__ pooled,
                            float* __restrict__ counts,
                            const float* __restrict__ bs1,
                            const float* __restrict__ bs2,
                            const float* __restrict__ bg,
                            const float* __restrict__ bbe) {
    int g = blockIdx.x;
    int chunk = blockIdx.y;   // 0..3
    int d = threadIdx.x;      // 320
    int s = lbound(batch, g);
    int e = lbound(batch, g + 1);
    if (chunk == 0 && d == 0) counts[g] = (float)(e - s);
    if (d >= DIM) return;
    const float invn = 1.0f / (float)N_NODES;
    float mean = bs1[d] * invn;
    float var = bs2[d] * invn - mean * mean;
    float sc = bg[d] * rsqrtf(var + BN_EPS);
    float sh = bbe[d] - mean * sc;
    int len = e - s;
    int per = (len + 3) >> 2;
    int r0 = s + chunk * per;
    int r1 = min(r0 + per, e);
    float a = 0.f;
    for (int r = r0; r < r1; ++r)
        a += fmaxf(bf2f(y_bf[(size_t)r * ADIM + d]) * sc + sh, 0.0f);
    if (r1 > r0) atomicAdd(&pooled[(size_t)g * DIM + d], a);
}

// ---------------- MLP head ----------------
__global__ void mlp1_kernel(const float* __restrict__ pooled,
                            const float* __restrict__ counts,
                            const float* __restrict__ Wc1,
                            const float* __restrict__ bc1,
                            float* __restrict__ hidden) {
    int g = blockIdx.x;
    int j = threadIdx.x;  // 192
    if (j >= DHALF) return;
    float inv = 1.0f / fmaxf(counts[g], 1.0f);
    const float* prow = pooled + (size_t)g * DIM;
    float acc = 0.0f;
    for (int k = 0; k < DIM; ++k) acc += prow[k] * Wc1[k * DHALF + j];
    hidden[g * DHALF + j] = fmaxf(acc * inv + bc1[j], 0.0f);
}

__global__ void mlp2_kernel(const float* __restrict__ hidden,
                            const float* __restrict__ Wc2,
                            const float* __restrict__ bc2,
                            float* __restrict__ out) {
    int idx = blockIdx.x * blockDim.x + threadIdx.x;
    if (idx >= NGRAPH * NCLS) return;
    int g = idx / NCLS;
    int c = idx - g * NCLS;
    const float* hrow = hidden + g * DHALF;
    float acc = bc2[c];
    for (int j = 0; j < DHALF; ++j) acc += hrow[j] * Wc2[j * NCLS + c];
    out[idx] = acc;
}

extern "C" void kernel_launch(void* const* d_in, const int* in_sizes, int n_in,
                              void* d_out, int out_size, void* d_ws, size_t ws_size,
                              hipStream_t stream) {
    const int*   x         = (const int*)d_in[0];
    const int*   edge_index= (const int*)d_in[1];
    const float* edge_attr = (const float*)d_in[2];
    const int*   batch     = (const int*)d_in[3];
    const float* node_emb  = (const float*)d_in[4];
    const float* edge_W    = (const float*)d_in[5];
    const float* edge_b    = (const float*)d_in[6];
    const float* eps       = (const float*)d_in[7];
    const float* W1        = (const float*)d_in[8];
    const float* g1        = (const float*)d_in[10];
    const float* be1       = (const float*)d_in[11];
    const float* W2        = (const float*)d_in[12];
    const float* g2        = (const float*)d_in[14];
    const float* be2       = (const float*)d_in[15];
    const float* Wc1       = (const float*)d_in[16];
    const float* bc1       = (const float*)d_in[17];
    const float* Wc2       = (const float*)d_in[18];
    const float* bc2       = (const float*)d_in[19];
    float* out = (float*)d_out;

    const int* src = edge_index;
    const int* dst = edge_index + N_EDGES;

    char* w = (char*)d_ws;
    size_t cur_off = 0;
    auto alloc = [&](size_t bytes) {
        char* p = w + cur_off;
        cur_off += (bytes + 63) & ~(size_t)63;
        return p;
    };
    const size_t AROW = (size_t)ROWS_PAD * ADIM;
    ushort_t* h_bf  = (ushort_t*)alloc(AROW * 2);   // layer-0 input
    ushort_t* zab   = (ushort_t*)alloc(AROW * 2);   // z
    ushort_t* y1bf  = (ushort_t*)alloc(AROW * 2);   // GEMM1 output
    ushort_t* y2bf  = (ushort_t*)alloc(AROW * 2);   // GEMM2 output (pre-BN2)
    ushort_t* Wt    = (ushort_t*)alloc((size_t)10 * ADIM * ADIM * 2);
    int*      deg   = (int*)alloc(N_NODES * 4);
    int*      off   = (int*)alloc((N_NODES + 1) * 4);
    int*      curp  = (int*)alloc(N_NODES * 4);
    int*      psrc  = (int*)alloc((size_t)N_EDGES * 4);
    float*    pea   = (float*)alloc((size_t)N_EDGES * 8 * 4);
    float*    sbuf  = (float*)alloc((size_t)N_LAYERS * 4 * ADIM * 4); // [L][4][ADIM]
    float*    pooled= (float*)alloc((size_t)NGRAPH * DIM * 4);
    float*    counts= (float*)alloc(NGRAPH * 4);
    float*    hidden= (float*)alloc((size_t)NGRAPH * DHALF * 4);

    auto sa1 = [&](int i) { return sbuf + ((size_t)i * 4 + 0) * ADIM; };
    auto sa2 = [&](int i) { return sbuf + ((size_t)i * 4 + 1) * ADIM; };
    auto sb1 = [&](int i) { return sbuf + ((size_t)i * 4 + 2) * ADIM; };
    auto sb2 = [&](int i) { return sbuf + ((size_t)i * 4 + 3) * ADIM; };

    // ---- prep ----
    hipMemsetAsync(deg, 0, N_NODES * 4, stream);
    hipMemsetAsync(zab + (size_t)N_NODES * ADIM, 0,
                   (size_t)(ROWS_PAD - N_NODES) * ADIM * 2, stream);
    hipMemsetAsync(sbuf, 0, (size_t)N_LAYERS * 4 * ADIM * 4, stream);

    node_enc_kernel<<<CDIV(N_NODES * 40, 256), 256, 0, stream>>>(x, node_emb, h_bf);
    wt_prep_kernel<<<CDIV(10 * ADIM * ADIM, 256), 256, 0, stream>>>(W1, W2, Wt);
    deg_kernel<<<CDIV(N_EDGES, 256), 256, 0, stream>>>(dst, deg);
    scan_kernel<<<1, 1024, 0, stream>>>(deg, off, curp);
    scatter_kernel<<<CDIV(N_EDGES, 256), 256, 0, stream>>>(src, dst, edge_attr,
                                                           curp, psrc, pea);

    const int GEMM_BLOCKS = (ROWS_PAD / 128) * 4;  // 640

    for (int i = 0; i < N_LAYERS; ++i) {
        // z = (1+eps)*h + agg, h = relu(BN2(y2_{i-1})) inline for i>0
        if (i == 0)
            msg_kernel<false><<<MSG_BLOCKS, 256, 0, stream>>>(
                h_bf, zab, off, psrc, pea, edge_W, edge_b, eps, i,
                nullptr, nullptr, nullptr, nullptr);
        else
            msg_kernel<true><<<MSG_BLOCKS, 256, 0, stream>>>(
                y2bf, zab, off, psrc, pea, edge_W, edge_b, eps, i,
                sb1(i - 1), sb2(i - 1), g2 + (i - 1) * DIM, be2 + (i - 1) * DIM);
        // y1 = z @ W1, stats -> sa(i)
        gemm_kernel<false><<<GEMM_BLOCKS, 256, 0, stream>>>(
            zab, Wt + (size_t)i * ADIM * ADIM, y1bf,
            nullptr, nullptr, nullptr, nullptr, sa1(i), sa2(i));
        // y2 = relu(BN1(y1)) @ W2 (BN1 fused into staging), stats -> sb(i)
        gemm_kernel<true><<<GEMM_BLOCKS, 256, 0, stream>>>(
            y1bf, Wt + (size_t)(5 + i) * ADIM * ADIM, y2bf,
            sa1(i), sa2(i), g1 + i * DIM, be1 + i * DIM, sb1(i), sb2(i));
    }

    hipMemsetAsync(pooled, 0, (size_t)NGRAPH * DIM * 4, stream);
    dim3 pgrid(NGRAPH, 4);
    pool_kernel<<<pgrid, ADIM, 0, stream>>>(y2bf, batch, pooled, counts,
                                            sb1(N_LAYERS - 1), sb2(N_LAYERS - 1),
                                            g2 + (N_LAYERS - 1) * DIM,
                                            be2 + (N_LAYERS - 1) * DIM);
    mlp1_kernel<<<NGRAPH, 192, 0, stream>>>(pooled, counts, Wc1, bc1, hidden);
    mlp2_kernel<<<CDIV(NGRAPH * NCLS, 256), 256, 0, stream>>>(hidden, Wc2, bc2, out);
}